// Round 13
// baseline (418.285 us; speedup 1.0000x reference)
//
#include <hip/hip_runtime.h>
#include <math.h>
#include <stdint.h>

// ---------------------------------------------------------------------------
// PSTTransformer: B=2, T=4, N=1024, m=256, L=4, K=32, C=512, H=8, Dh=64,
// MLP=2048, DEPTH=2.
// R12: GEMM K-loop double-buffered (prefetch-after-barrier, same pattern as
//      attn): async16 prefetch of tile k+1 overlaps MFMA on tile k, draining
//      at the next barrier instead of stalling this one. Bit-identical math.
//      LN-fold pipeline (R11), fps floor (R7), attn (R8) unchanged.
// ---------------------------------------------------------------------------

typedef __bf16 bf16_t;
typedef __bf16 bf16x8 __attribute__((ext_vector_type(8)));
typedef __bf16 bf16x4 __attribute__((ext_vector_type(4)));
typedef float f32x4 __attribute__((ext_vector_type(4)));

__device__ __forceinline__ void async16(const bf16_t* g, bf16_t* l) {
  __builtin_amdgcn_global_load_lds(
      (const __attribute__((address_space(1))) void*)g,
      (__attribute__((address_space(3))) void*)l, 16, 0, 0);
}

__device__ __forceinline__ float wave_max_dpp(float v) {
  int a = __float_as_int(v);
  int t;
  t = __builtin_amdgcn_update_dpp(a, a, 0x111, 0xf, 0xf, false);
  a = __float_as_int(fmaxf(__int_as_float(a), __int_as_float(t)));
  t = __builtin_amdgcn_update_dpp(a, a, 0x112, 0xf, 0xf, false);
  a = __float_as_int(fmaxf(__int_as_float(a), __int_as_float(t)));
  t = __builtin_amdgcn_update_dpp(a, a, 0x114, 0xf, 0xf, false);
  a = __float_as_int(fmaxf(__int_as_float(a), __int_as_float(t)));
  t = __builtin_amdgcn_update_dpp(a, a, 0x118, 0xf, 0xf, false);
  a = __float_as_int(fmaxf(__int_as_float(a), __int_as_float(t)));
  t = __builtin_amdgcn_update_dpp(a, a, 0x142, 0xf, 0xf, false);
  a = __float_as_int(fmaxf(__int_as_float(a), __int_as_float(t)));
  t = __builtin_amdgcn_update_dpp(a, a, 0x143, 0xf, 0xf, false);
  a = __float_as_int(fmaxf(__int_as_float(a), __int_as_float(t)));
  return __int_as_float(a);
}

template <int CTRL>
__device__ __forceinline__ unsigned long long dpp_max_u64(unsigned long long kv) {
  uint32_t lo = (uint32_t)kv, hi = (uint32_t)(kv >> 32);
  uint32_t lo2 =
      (uint32_t)__builtin_amdgcn_update_dpp((int)lo, (int)lo, CTRL, 0xf, 0xf, false);
  uint32_t hi2 =
      (uint32_t)__builtin_amdgcn_update_dpp((int)hi, (int)hi, CTRL, 0xf, 0xf, false);
  unsigned long long other = ((unsigned long long)hi2 << 32) | lo2;
  return other > kv ? other : kv;
}

// ============== FPS + weight cvt (g-folded) + stats-zero + LN consts ==============
__global__ __launch_bounds__(512) void fps_cvt_kernel(
    const float* __restrict__ xyzs, float* __restrict__ anchors,
    const float* __restrict__ s0, bf16_t* __restrict__ d0,
    const float* __restrict__ s1, bf16_t* __restrict__ d1,
    const float* __restrict__ s2, bf16_t* __restrict__ d2,
    const float* __restrict__ s3, bf16_t* __restrict__ d3,
    const float* __restrict__ ln1g, const float* __restrict__ ln1b,
    const float* __restrict__ ln2g, const float* __restrict__ ln2b,
    float* __restrict__ c2cb_q, float* __restrict__ c2cb_f,
    float* __restrict__ statsZ) {
  int bid = blockIdx.x;
  int tid = threadIdx.x;
  int w = tid >> 6, lane = tid & 63;
  if (bid >= 3086) {
    int wv = (bid - 3086) * 8 + w;
    const float* Wrow; const float* g; const float* bt; float* outp;
    if (wv < 3072) {
      int dep = wv / 1536, n = wv % 1536;
      Wrow = s0 + ((size_t)dep * 1536 + n) * 512;
      g = ln1g + dep * 512; bt = ln1b + dep * 512;
      outp = c2cb_q + (size_t)(dep * 1536 + n) * 2;
    } else {
      int v2 = wv - 3072;
      int dep = v2 / 2048, n = v2 % 2048;
      Wrow = s2 + ((size_t)dep * 2048 + n) * 512;
      g = ln2g + dep * 512; bt = ln2b + dep * 512;
      outp = c2cb_f + (size_t)(dep * 2048 + n) * 2;
    }
    float4 wa = ((const float4*)Wrow)[lane * 2], wb = ((const float4*)Wrow)[lane * 2 + 1];
    float4 ga = ((const float4*)g)[lane * 2], gb = ((const float4*)g)[lane * 2 + 1];
    float4 ba = ((const float4*)bt)[lane * 2], bb = ((const float4*)bt)[lane * 2 + 1];
    float c2 = wa.x * ga.x + wa.y * ga.y + wa.z * ga.z + wa.w * ga.w +
               wb.x * gb.x + wb.y * gb.y + wb.z * gb.z + wb.w * gb.w;
    float cb = wa.x * ba.x + wa.y * ba.y + wa.z * ba.z + wa.w * ba.w +
               wb.x * bb.x + wb.y * bb.y + wb.z * bb.z + wb.w * bb.w;
#pragma unroll
    for (int off = 32; off >= 1; off >>= 1) {
      c2 += __shfl_xor(c2, off, 64);
      cb += __shfl_xor(cb, off, 64);
    }
    if (lane == 0) { outp[0] = c2; outp[1] = cb; }
    return;
  }
  if (bid >= 8) {
    int idx = (bid - 8) * 512 + tid;
    if (idx < 1572864) {
      const float* s; bf16_t* d; int off;
      const float* gsc = nullptr; int c = 0;
      if (idx < 393216) {
        s = s0; d = d0; off = idx;
        gsc = ln1g + ((idx >= 196608) ? 512 : 0); c = (idx * 4) & 511;
      } else if (idx < 524288) { s = s1; d = d1; off = idx - 393216; }
      else if (idx < 1048576) {
        s = s2; d = d2; off = idx - 524288;
        gsc = ln2g + ((off >= 262144) ? 512 : 0); c = (off * 4) & 511;
      } else { s = s3; d = d3; off = idx - 1048576; }
      float4 v = ((const float4*)s)[off];
      if (gsc) {
        v.x *= gsc[c]; v.y *= gsc[c + 1]; v.z *= gsc[c + 2]; v.w *= gsc[c + 3];
      }
      bf16x4 o = {(bf16_t)v.x, (bf16_t)v.y, (bf16_t)v.z, (bf16_t)v.w};
      ((bf16x4*)d)[off] = o;
    } else {
      ((float4*)statsZ)[idx - 1572864] = make_float4(0.f, 0.f, 0.f, 0.f);
    }
    return;
  }
  int to = bid & 3, b = bid >> 2;
  const float* fr = xyzs + (size_t)(b * 4 + to) * 1024 * 3;
  float* an = anchors + (size_t)(b * 4 + to) * 256 * 3;
  __shared__ __align__(16) float4 sp[1024];
  __shared__ __align__(16) unsigned long long keys[2][8];
  float px[2], py[2], pz[2], dist[2];
#pragma unroll
  for (int r = 0; r < 2; ++r) {
    int i = r * 512 + tid;
    float x = fr[i * 3 + 0], y = fr[i * 3 + 1], z = fr[i * 3 + 2];
    px[r] = x; py[r] = y; pz[r] = z; dist[r] = 1e10f;
    sp[i] = make_float4(x, y, z, 0.0f);
  }
  __syncthreads();
  float4 c = sp[0];
  if (tid == 0) { an[0] = c.x; an[1] = c.y; an[2] = c.z; }
  for (int s = 1; s < 256; ++s) {
    int par = s & 1;
#pragma unroll
    for (int r = 0; r < 2; ++r) {
      float dx = px[r] - c.x, dy = py[r] - c.y, dz = pz[r] - c.z;
      float d = fmaf(dx, dx, fmaf(dy, dy, dz * dz));
      dist[r] = fminf(dist[r], d);
    }
    float mloc = fmaxf(dist[0], dist[1]);
    float wmax = wave_max_dpp(mloc);
    float smax = __int_as_float(__builtin_amdgcn_readlane(__float_as_int(wmax), 63));
    unsigned int cidx = 0xFFFFFFFFu;
#pragma unroll
    for (int r = 1; r >= 0; --r) {
      unsigned long long m = __ballot(dist[r] == smax);
      unsigned int tz = (unsigned int)__builtin_ctzll(m | 0x8000000000000000ull);
      unsigned int cand = (unsigned int)(r * 512 + w * 64) + tz;
      cidx = m ? cand : cidx;
    }
    unsigned long long key =
        ((unsigned long long)__float_as_uint(smax) << 32) |
        (unsigned long long)(~cidx);
    if (lane == 0) keys[par][w] = key;
    __syncthreads();
    unsigned long long kv = keys[par][lane & 7];
    kv = dpp_max_u64<0xB1>(kv);
    kv = dpp_max_u64<0x4E>(kv);
    kv = dpp_max_u64<0x124>(kv);
    unsigned int bi = ~(unsigned int)(kv & 0xFFFFFFFFull);
    c = sp[bi];
    if (tid == 0) { an[s * 3 + 0] = c.x; an[s * 3 + 1] = c.y; an[s * 3 + 2] = c.z; }
  }
}

// ========== Ball query + P4D conv + ReLU; emits fp32 + bf16 + exact row stats ==========
__global__ __launch_bounds__(256) void conv_kernel(
    const float* __restrict__ xyzs, const float* __restrict__ anchors,
    const float* __restrict__ Wd, float* __restrict__ feats,
    bf16_t* __restrict__ featsb, float* __restrict__ stA0) {
  int bid = blockIdx.x;
  int tid = threadIdx.x;
  int j = bid & 255, to = (bid >> 8) & 3, b = bid >> 10;
  __shared__ float disp[96][4];
  __shared__ int idxbuf[3][32];
  __shared__ float red1[4], red2[4];
  const float* an = anchors + (size_t)((b * 4 + to) * 256 + j) * 3;
  float ax = an[0], ay = an[1], az = an[2];
  int w = tid >> 6, lane = tid & 63;
  if (w < 3) {
    int src = to + w - 1; src = src < 0 ? 0 : (src > 3 ? 3 : src);
    const float* nb = xyzs + (size_t)(b * 4 + src) * 1024 * 3;
    int cnt = 0;
    for (int ch = 0; ch < 16; ++ch) {
      if (cnt >= 32) break;
      int i = ch * 64 + lane;
      float dx = ax - nb[i * 3], dy = ay - nb[i * 3 + 1], dz = az - nb[i * 3 + 2];
      float d2 = dx * dx + dy * dy + dz * dz;
      bool in = d2 < 1.0f;
      unsigned long long mask = __ballot(in);
      if (in) {
        int pos = cnt + (int)__popcll(mask & ((1ull << lane) - 1ull));
        if (pos < 32) idxbuf[w][pos] = i;
      }
      cnt += (int)__popcll(mask);
    }
    if (cnt > 32) cnt = 32;
    if (lane >= cnt && lane < 32) idxbuf[w][lane] = (cnt > 0) ? idxbuf[w][0] : 0;
    if (lane < 32) {
      int ni = idxbuf[w][lane];
      int row = w * 32 + lane;
      disp[row][0] = nb[ni * 3 + 0] - ax;
      disp[row][1] = nb[ni * 3 + 1] - ay;
      disp[row][2] = nb[ni * 3 + 2] - az;
      disp[row][3] = (float)(w - 1);
    }
  }
  __syncthreads();
  int row = (b * 1024) + to * 256 + j;
  const float* wr0 = Wd + tid * 4;
  const float* wr1 = Wd + (tid + 256) * 4;
  float w00 = wr0[0], w01 = wr0[1], w02 = wr0[2], w03 = wr0[3];
  float w10 = wr1[0], w11 = wr1[1], w12 = wr1[2], w13 = wr1[3];
  float mx0 = -1e30f, mx1 = -1e30f;
#pragma unroll 8
  for (int nn = 0; nn < 96; ++nn) {
    float a0 = disp[nn][0], a1 = disp[nn][1], a2 = disp[nn][2], a3 = disp[nn][3];
    mx0 = fmaxf(mx0, a0 * w00 + a1 * w01 + a2 * w02 + a3 * w03);
    mx1 = fmaxf(mx1, a0 * w10 + a1 * w11 + a2 * w12 + a3 * w13);
  }
  float v0 = fmaxf(mx0, 0.0f), v1 = fmaxf(mx1, 0.0f);
  float* fout = feats + (size_t)row * 512;
  fout[tid] = v0;
  fout[tid + 256] = v1;
  featsb[(size_t)row * 512 + tid] = (bf16_t)v0;
  featsb[(size_t)row * 512 + tid + 256] = (bf16_t)v1;
  float s = v0 + v1;
  float q = v0 * v0 + v1 * v1;
#pragma unroll
  for (int off = 32; off >= 1; off >>= 1) {
    s += __shfl_xor(s, off, 64);
    q += __shfl_xor(q, off, 64);
  }
  if (lane == 0) { red1[w] = s; red2[w] = q; }
  __syncthreads();
  if (tid == 0) {
    stA0[2 * row] = red1[0] + red1[1] + red1[2] + red1[3];
    stA0[2 * row + 1] = red2[0] + red2[1] + red2[2] + red2[3];
  }
}

// ========================= bf16 MFMA GEMM (BK=64, double-buffered) =========================
// Prefetch-after-barrier: tile k+1's async16s issue right after the barrier
// and drain at the NEXT barrier, overlapping this tile's MFMAs (attn pattern).
template <int BM, int BN, bool GELU, bool BIAS, bool RES, bool OUTBF,
          bool LNIN, bool STATS>
__global__ __launch_bounds__(256) void gemm_bf16(
    const bf16_t* __restrict__ A, const bf16_t* __restrict__ W,
    const float* __restrict__ bias, const float* __restrict__ res,
    void* __restrict__ Cout, int Mn, int Nn, int Kn,
    const float* __restrict__ stats, const float* __restrict__ c2cb,
    float* __restrict__ statsOut, bf16_t* __restrict__ bcopy) {
  constexpr int BK = 64;
  constexpr int WM = BM / 2, WN = BN / 2;
  constexpr int MT = WM / 16, NT = WN / 16;
  constexpr int AIT = (BM * BK / 8) / 256;
  constexpr int BIT = (BN * BK / 8) / 256;
  __shared__ __align__(16) bf16_t As[2][BM * BK];
  __shared__ __align__(16) bf16_t Bs[2][BN * BK];
  int tid = threadIdx.x;
  int w = tid >> 6, lane = tid & 63;
  int wr = w >> 1, wc = w & 1;
  int m0 = blockIdx.y * BM, n0 = blockIdx.x * BN;
  int l15 = lane & 15, quad = lane >> 4;
  f32x4 acc[MT][NT] = {};

  const int a_fo = (wr * WM + l15) * BK + quad * 8;
  const int b_fo = (wc * WN + l15) * BK + quad * 8;

  auto stageg = [&](int k0, int buf) {
#pragma unroll
    for (int i = 0; i < AIT; ++i) {
      int chunk = i * 256 + tid;
      int row = chunk >> 3, c8 = chunk & 7;
      async16(A + ((size_t)(m0 + row) * Kn + k0 + c8 * 8), As[buf] + chunk * 8);
    }
#pragma unroll
    for (int i = 0; i < BIT; ++i) {
      int chunk = i * 256 + tid;
      int row = chunk >> 3, c8 = chunk & 7;
      async16(W + ((size_t)(n0 + row) * Kn + k0 + c8 * 8), Bs[buf] + chunk * 8);
    }
  };

  int nIter = Kn / BK;
  stageg(0, 0);
  for (int it = 0; it < nIter; ++it) {
    int cur = it & 1;
    __syncthreads();  // drains cur's staging (vmcnt(0) before barrier)
    if (it + 1 < nIter) stageg((it + 1) * BK, cur ^ 1);  // flies during MFMA
#pragma unroll
    for (int ks = 0; ks < 2; ++ks) {
      bf16x8 aF[MT], bF[NT];
#pragma unroll
      for (int mt = 0; mt < MT; ++mt)
        aF[mt] = *(const bf16x8*)&As[cur][a_fo + mt * 16 * BK + ks * 32];
#pragma unroll
      for (int nt = 0; nt < NT; ++nt)
        bF[nt] = *(const bf16x8*)&Bs[cur][b_fo + nt * 16 * BK + ks * 32];
#pragma unroll
      for (int mt = 0; mt < MT; ++mt)
#pragma unroll
        for (int nt = 0; nt < NT; ++nt)
          acc[mt][nt] = __builtin_amdgcn_mfma_f32_16x16x32_bf16(
              aF[mt], bF[nt], acc[mt][nt], 0, 0, 0);
    }
  }
  int rbase = quad * 4;
#pragma unroll
  for (int mt = 0; mt < MT; ++mt) {
#pragma unroll
    for (int reg = 0; reg < 4; ++reg) {
      int r = m0 + wr * WM + mt * 16 + rbase + reg;
      size_t roff = (size_t)r * Nn;
      float mu = 0.f, rs = 0.f;
      if (LNIN) {
        float s1 = stats[2 * r], s2 = stats[2 * r + 1];
        mu = s1 * (1.0f / 512.0f);
        float var = s2 * (1.0f / 512.0f) - mu * mu;
        rs = rsqrtf(var + 1e-5f);
      }
      float rsum = 0.f, rsq = 0.f;
#pragma unroll
      for (int nt = 0; nt < NT; ++nt) {
        int c = n0 + wc * WN + nt * 16 + l15;
        float v = acc[mt][nt][reg];
        if (LNIN) {
          float cc2 = c2cb[2 * c], ccb = c2cb[2 * c + 1];
          v = rs * v - rs * mu * cc2 + ccb;
        }
        if (BIAS) v += bias[c];
        if (GELU) v = v * 0.5f * (1.0f + erff(v * 0.7071067811865475f));
        if (RES) v += res[roff + c];
        if (OUTBF) ((bf16_t*)Cout)[roff + c] = (bf16_t)v;
        else ((float*)Cout)[roff + c] = v;
        if (STATS) {
          bcopy[roff + c] = (bf16_t)v;
          rsum += v; rsq += v * v;
        }
      }
      if (STATS) {
#pragma unroll
        for (int off = 1; off <= 8; off <<= 1) {
          rsum += __shfl_xor(rsum, off, 64);
          rsq += __shfl_xor(rsq, off, 64);
        }
        if (l15 == 0) {
          atomicAdd(&statsOut[2 * r], rsum);
          atomicAdd(&statsOut[2 * r + 1], rsq);
        }
      }
    }
  }
}

// ========================= Attention (MFMA flash, double-buffered) =========================
__global__ __launch_bounds__(256) void attn_kernel(
    const bf16_t* __restrict__ qkv, const float* __restrict__ xyzf,
    const float* __restrict__ Wsp, bf16_t* __restrict__ outp) {
  int bid = blockIdx.x;
  int qt = bid & 15, h = (bid >> 4) & 7, b = bid >> 7;
  int tid = threadIdx.x;
  int w = tid >> 6, lane = tid & 63;
  int l15 = lane & 15, quad = lane >> 4;

  __shared__ __align__(16) bf16_t Kb[2][64 * 64];
  __shared__ __align__(16) bf16_t Vt[2][64 * 72];
  __shared__ __align__(16) bf16_t Ps[4][16 * 72];
  __shared__ __align__(16) float4 Xs[2][64];

  const size_t tokbase = (size_t)b * 1024;
  int qbase = qt * 64 + w * 16;

  bf16x8 aQ[2];
  {
    const bf16_t* qp = qkv + (tokbase + qbase + l15) * 1536 + h * 64 + quad * 8;
    aQ[0] = *(const bf16x8*)(qp);
    aQ[1] = *(const bf16x8*)(qp + 32);
  }

  f32x4 oacc[4] = {};
  float lr[4] = {}, pxr[4] = {}, pyr[4] = {}, pzr[4] = {};

  auto stage = [&](int ch, int buf) {
    int j0 = ch * 64;
    int r0 = tid >> 3, seg = tid & 7;
    const bf16_t* g0 = qkv + (tokbase + j0 + r0) * 1536 + 512 + h * 64 + seg * 8;
    async16(g0, Kb[buf] + tid * 8);
    const bf16_t* g1 = qkv + (tokbase + j0 + 32 + r0) * 1536 + 512 + h * 64 + seg * 8;
    async16(g1, Kb[buf] + 2048 + tid * 8);
#pragma unroll
    for (int t = 0; t < 4; ++t) {
      int task = t * 256 + tid;
      int rp = task >> 5, c2 = task & 31;
      const uint32_t* vsrc = (const uint32_t*)(qkv + (tokbase + j0 + 2 * rp) * 1536 +
                                               1024 + h * 64 + 2 * c2);
      uint32_t a = vsrc[0];
      uint32_t bq = vsrc[768];
      uint32_t wlo = (a & 0xffffu) | (bq << 16);
      uint32_t whi = (a >> 16) | (bq & 0xffff0000u);
      uint32_t* vd = (uint32_t*)Vt[buf];
      vd[c2 * 72 + rp] = wlo;
      vd[c2 * 72 + 36 + rp] = whi;
    }
    if (tid < 64) {
      const float* xp = xyzf + (tokbase + j0 + tid) * 3;
      Xs[buf][tid] = make_float4(xp[0], xp[1], xp[2], 0.0f);
    }
  };

  stage(0, 0);
  for (int ch = 0; ch < 16; ++ch) {
    int cur = ch & 1;
    __syncthreads();
    if (ch + 1 < 16) stage(ch + 1, cur ^ 1);
    f32x4 sacc[4] = {};
#pragma unroll
    for (int ks = 0; ks < 2; ++ks)
#pragma unroll
      for (int nt = 0; nt < 4; ++nt) {
        bf16x8 bK = *(const bf16x8*)&Kb[cur][(nt * 16 + l15) * 64 + ks * 32 + quad * 8];
        sacc[nt] = __builtin_amdgcn_mfma_f32_16x16x32_bf16(aQ[ks], bK, sacc[nt], 0, 0, 0);
      }
#pragma unroll
    for (int nt = 0; nt < 4; ++nt) {
      float4 xk = Xs[cur][nt * 16 + l15];
#pragma unroll
      for (int reg = 0; reg < 4; ++reg) {
        float p = __expf(sacc[nt][reg] * 0.125f);
        bf16_t pb = (bf16_t)p;
        float pf = (float)pb;
        Ps[w][(quad * 4 + reg) * 72 + nt * 16 + l15] = pb;
        lr[reg] += pf;
        pxr[reg] = fmaf(pf, xk.x, pxr[reg]);
        pyr[reg] = fmaf(pf, xk.y, pyr[reg]);
        pzr[reg] = fmaf(pf, xk.z, pzr[reg]);
      }
    }
    bf16x8 aP[2];
    aP[0] = *(const bf16x8*)&Ps[w][l15 * 72 + quad * 8];
    aP[1] = *(const bf16x8*)&Ps[w][l15 * 72 + 32 + quad * 8];
#pragma unroll
    for (int ks = 0; ks < 2; ++ks)
#pragma unroll
      for (int ct = 0; ct < 4; ++ct) {
        bf16x8 bV = *(const bf16x8*)&Vt[cur][(ct * 16 + l15) * 72 + ks * 32 + quad * 8];
        oacc[ct] = __builtin_amdgcn_mfma_f32_16x16x32_bf16(aP[ks], bV, oacc[ct], 0, 0, 0);
      }
  }
#pragma unroll
  for (int reg = 0; reg < 4; ++reg) {
#pragma unroll
    for (int off = 1; off <= 8; off <<= 1) {
      lr[reg] += __shfl_xor(lr[reg], off, 64);
      pxr[reg] += __shfl_xor(pxr[reg], off, 64);
      pyr[reg] += __shfl_xor(pyr[reg], off, 64);
      pzr[reg] += __shfl_xor(pzr[reg], off, 64);
    }
  }
#pragma unroll
  for (int reg = 0; reg < 4; ++reg) {
    size_t tok = tokbase + qbase + quad * 4 + reg;
    float inv = 1.0f / lr[reg];
    const float* xqp = xyzf + tok * 3;
    float wd0 = pxr[reg] * inv - xqp[0];
    float wd1 = pyr[reg] * inv - xqp[1];
    float wd2 = pzr[reg] * inv - xqp[2];
#pragma unroll
    for (int ct = 0; ct < 4; ++ct) {
      int c = ct * 16 + l15;
      const float* wr = Wsp + c * 3;
      float dv = wd0 * wr[0] + wd1 * wr[1] + wd2 * wr[2];
      outp[tok * 512 + h * 64 + c] = (bf16_t)(oacc[ct][reg] * inv + dv);
    }
  }
}

// ========================= launch =========================
extern "C" void kernel_launch(void* const* d_in, const int* in_sizes, int n_in,
                              void* d_out, int out_size, void* d_ws, size_t ws_size,
                              hipStream_t stream) {
  const float* xyzs = (const float*)d_in[0];
  const float* Wd   = (const float*)d_in[1];
  const float* Wqkv = (const float*)d_in[2];
  const float* Wsp  = (const float*)d_in[3];
  const float* Wout = (const float*)d_in[4];
  const float* bout = (const float*)d_in[5];
  const float* ln1g = (const float*)d_in[6];
  const float* ln1b = (const float*)d_in[7];
  const float* Wff1 = (const float*)d_in[8];
  const float* bff1 = (const float*)d_in[9];
  const float* Wff2 = (const float*)d_in[10];
  const float* bff2 = (const float*)d_in[11];
  const float* ln2g = (const float*)d_in[12];
  const float* ln2b = (const float*)d_in[13];
  float* out = (float*)d_out;

  float* ws = (float*)d_ws;
  float* anchors = ws;                         // 8192 f32
  float* featsA  = ws + 8192;                  // 2048*512 f32
  float* featsB  = featsA + 1048576;           // 2048*512 f32
  float* big     = featsB + 1048576;           // 12MB region
  bf16_t* bigb   = (bf16_t*)big;               // qkv out / ff1 out bf16
  bf16_t* featsAb = (bf16_t*)(big + 3145728);  // 2048*512 bf16 (raw x)
  bf16_t* attob  = featsAb + 1048576;          // 2048*512 bf16
  bf16_t* featsBb = attob + 1048576;           // 2048*512 bf16 (raw x)
  bf16_t* wq_b   = featsBb + 1048576;          // 2*1536*512
  bf16_t* wo_b   = wq_b + 1572864;             // 2*512*512
  bf16_t* w1_b   = wo_b + 524288;              // 2*2048*512
  bf16_t* w2_b   = w1_b + 2097152;             // 2*512*2048
  float* stA0    = (float*)(w2_b + 2097152);   // 4096 f (exact, conv)
  float* statsZ  = stA0 + 4096;                // 12288 f zeroed: stB0|stB1|stA1
  float* stB0    = statsZ;
  float* stB1    = statsZ + 4096;
  float* stA1    = statsZ + 8192;
  float* c2cb_q  = statsZ + 12288;             // 2*1536*2 f
  float* c2cb_f  = c2cb_q + 6144;              // 2*2048*2 f

  fps_cvt_kernel<<<3982, 512, 0, stream>>>(
      xyzs, anchors, Wqkv, wq_b, Wout, wo_b, Wff1, w1_b, Wff2, w2_b,
      ln1g, ln1b, ln2g, ln2b, c2cb_q, c2cb_f, statsZ);
  conv_kernel<<<2048, 256, 0, stream>>>(xyzs, anchors, Wd, featsA, featsAb, stA0);

  for (int dep = 0; dep < 2; ++dep) {
    const float* stA = dep ? stA1 : stA0;
    float* stB = dep ? stB1 : stB0;
    gemm_bf16<64, 128, false, false, false, true, true, false>
        <<<dim3(12, 32), 256, 0, stream>>>(
        featsAb, wq_b + (size_t)dep * 786432, nullptr, nullptr, bigb,
        2048, 1536, 512, stA, c2cb_q + (size_t)dep * 3072, nullptr, nullptr);
    attn_kernel<<<256, 256, 0, stream>>>(bigb, anchors, Wsp + dep * 192, attob);
    gemm_bf16<32, 64, true, true, true, false, false, true>
        <<<dim3(8, 64), 256, 0, stream>>>(
        attob, wo_b + (size_t)dep * 262144, bout + dep * 512, featsA, featsB,
        2048, 512, 512, nullptr, nullptr, stB, featsBb);
    gemm_bf16<64, 128, true, true, false, true, true, false>
        <<<dim3(16, 32), 256, 0, stream>>>(
        featsBb, w1_b + (size_t)dep * 1048576, bff1 + dep * 2048, nullptr, bigb,
        2048, 2048, 512, stB, c2cb_f + (size_t)dep * 4096, nullptr, nullptr);
    if (dep == 0) {
      gemm_bf16<32, 64, false, true, true, false, false, true>
          <<<dim3(8, 64), 256, 0, stream>>>(
          bigb, w2_b, bff2, featsB, featsA,
          2048, 512, 2048, nullptr, nullptr, stA1, featsAb);
    } else {
      gemm_bf16<32, 64, false, true, true, false, false, false>
          <<<dim3(8, 64), 256, 0, stream>>>(
          bigb, w2_b + 1048576, bff2 + 512, featsB, out,
          2048, 512, 2048, nullptr, nullptr, nullptr, nullptr);
    }
  }
}

// Round 14
// 402.953 us; speedup vs baseline: 1.0380x; 1.0380x over previous
//
#include <hip/hip_runtime.h>
#include <math.h>
#include <stdint.h>

// ---------------------------------------------------------------------------
// PSTTransformer: B=2, T=4, N=1024, m=256, L=4, K=32, C=512, H=8, Dh=64,
// MLP=2048, DEPTH=2.
// R13: GEMM dbuf REVERTED (R12 halved blocks/CU: 24->49KB LDS; occupancy
//      is the currency -- m132 lesson). Single-buffer BK=64 K-loop (R11).
//      qkv/ff1 tiles 64x128 -> 64x64: 768/1024 blocks = 3-4/CU balanced
//      (was 384 = 1.5/CU imbalanced). Bit-identical accumulation order.
// ---------------------------------------------------------------------------

typedef __bf16 bf16_t;
typedef __bf16 bf16x8 __attribute__((ext_vector_type(8)));
typedef __bf16 bf16x4 __attribute__((ext_vector_type(4)));
typedef float f32x4 __attribute__((ext_vector_type(4)));

__device__ __forceinline__ void async16(const bf16_t* g, bf16_t* l) {
  __builtin_amdgcn_global_load_lds(
      (const __attribute__((address_space(1))) void*)g,
      (__attribute__((address_space(3))) void*)l, 16, 0, 0);
}

__device__ __forceinline__ float wave_max_dpp(float v) {
  int a = __float_as_int(v);
  int t;
  t = __builtin_amdgcn_update_dpp(a, a, 0x111, 0xf, 0xf, false);
  a = __float_as_int(fmaxf(__int_as_float(a), __int_as_float(t)));
  t = __builtin_amdgcn_update_dpp(a, a, 0x112, 0xf, 0xf, false);
  a = __float_as_int(fmaxf(__int_as_float(a), __int_as_float(t)));
  t = __builtin_amdgcn_update_dpp(a, a, 0x114, 0xf, 0xf, false);
  a = __float_as_int(fmaxf(__int_as_float(a), __int_as_float(t)));
  t = __builtin_amdgcn_update_dpp(a, a, 0x118, 0xf, 0xf, false);
  a = __float_as_int(fmaxf(__int_as_float(a), __int_as_float(t)));
  t = __builtin_amdgcn_update_dpp(a, a, 0x142, 0xf, 0xf, false);
  a = __float_as_int(fmaxf(__int_as_float(a), __int_as_float(t)));
  t = __builtin_amdgcn_update_dpp(a, a, 0x143, 0xf, 0xf, false);
  a = __float_as_int(fmaxf(__int_as_float(a), __int_as_float(t)));
  return __int_as_float(a);
}

template <int CTRL>
__device__ __forceinline__ unsigned long long dpp_max_u64(unsigned long long kv) {
  uint32_t lo = (uint32_t)kv, hi = (uint32_t)(kv >> 32);
  uint32_t lo2 =
      (uint32_t)__builtin_amdgcn_update_dpp((int)lo, (int)lo, CTRL, 0xf, 0xf, false);
  uint32_t hi2 =
      (uint32_t)__builtin_amdgcn_update_dpp((int)hi, (int)hi, CTRL, 0xf, 0xf, false);
  unsigned long long other = ((unsigned long long)hi2 << 32) | lo2;
  return other > kv ? other : kv;
}

// ============== FPS + weight cvt (g-folded) + stats-zero + LN consts ==============
__global__ __launch_bounds__(512) void fps_cvt_kernel(
    const float* __restrict__ xyzs, float* __restrict__ anchors,
    const float* __restrict__ s0, bf16_t* __restrict__ d0,
    const float* __restrict__ s1, bf16_t* __restrict__ d1,
    const float* __restrict__ s2, bf16_t* __restrict__ d2,
    const float* __restrict__ s3, bf16_t* __restrict__ d3,
    const float* __restrict__ ln1g, const float* __restrict__ ln1b,
    const float* __restrict__ ln2g, const float* __restrict__ ln2b,
    float* __restrict__ c2cb_q, float* __restrict__ c2cb_f,
    float* __restrict__ statsZ) {
  int bid = blockIdx.x;
  int tid = threadIdx.x;
  int w = tid >> 6, lane = tid & 63;
  if (bid >= 3086) {
    int wv = (bid - 3086) * 8 + w;
    const float* Wrow; const float* g; const float* bt; float* outp;
    if (wv < 3072) {
      int dep = wv / 1536, n = wv % 1536;
      Wrow = s0 + ((size_t)dep * 1536 + n) * 512;
      g = ln1g + dep * 512; bt = ln1b + dep * 512;
      outp = c2cb_q + (size_t)(dep * 1536 + n) * 2;
    } else {
      int v2 = wv - 3072;
      int dep = v2 / 2048, n = v2 % 2048;
      Wrow = s2 + ((size_t)dep * 2048 + n) * 512;
      g = ln2g + dep * 512; bt = ln2b + dep * 512;
      outp = c2cb_f + (size_t)(dep * 2048 + n) * 2;
    }
    float4 wa = ((const float4*)Wrow)[lane * 2], wb = ((const float4*)Wrow)[lane * 2 + 1];
    float4 ga = ((const float4*)g)[lane * 2], gb = ((const float4*)g)[lane * 2 + 1];
    float4 ba = ((const float4*)bt)[lane * 2], bb = ((const float4*)bt)[lane * 2 + 1];
    float c2 = wa.x * ga.x + wa.y * ga.y + wa.z * ga.z + wa.w * ga.w +
               wb.x * gb.x + wb.y * gb.y + wb.z * gb.z + wb.w * gb.w;
    float cb = wa.x * ba.x + wa.y * ba.y + wa.z * ba.z + wa.w * ba.w +
               wb.x * bb.x + wb.y * bb.y + wb.z * bb.z + wb.w * bb.w;
#pragma unroll
    for (int off = 32; off >= 1; off >>= 1) {
      c2 += __shfl_xor(c2, off, 64);
      cb += __shfl_xor(cb, off, 64);
    }
    if (lane == 0) { outp[0] = c2; outp[1] = cb; }
    return;
  }
  if (bid >= 8) {
    int idx = (bid - 8) * 512 + tid;
    if (idx < 1572864) {
      const float* s; bf16_t* d; int off;
      const float* gsc = nullptr; int c = 0;
      if (idx < 393216) {
        s = s0; d = d0; off = idx;
        gsc = ln1g + ((idx >= 196608) ? 512 : 0); c = (idx * 4) & 511;
      } else if (idx < 524288) { s = s1; d = d1; off = idx - 393216; }
      else if (idx < 1048576) {
        s = s2; d = d2; off = idx - 524288;
        gsc = ln2g + ((off >= 262144) ? 512 : 0); c = (off * 4) & 511;
      } else { s = s3; d = d3; off = idx - 1048576; }
      float4 v = ((const float4*)s)[off];
      if (gsc) {
        v.x *= gsc[c]; v.y *= gsc[c + 1]; v.z *= gsc[c + 2]; v.w *= gsc[c + 3];
      }
      bf16x4 o = {(bf16_t)v.x, (bf16_t)v.y, (bf16_t)v.z, (bf16_t)v.w};
      ((bf16x4*)d)[off] = o;
    } else {
      ((float4*)statsZ)[idx - 1572864] = make_float4(0.f, 0.f, 0.f, 0.f);
    }
    return;
  }
  int to = bid & 3, b = bid >> 2;
  const float* fr = xyzs + (size_t)(b * 4 + to) * 1024 * 3;
  float* an = anchors + (size_t)(b * 4 + to) * 256 * 3;
  __shared__ __align__(16) float4 sp[1024];
  __shared__ __align__(16) unsigned long long keys[2][8];
  float px[2], py[2], pz[2], dist[2];
#pragma unroll
  for (int r = 0; r < 2; ++r) {
    int i = r * 512 + tid;
    float x = fr[i * 3 + 0], y = fr[i * 3 + 1], z = fr[i * 3 + 2];
    px[r] = x; py[r] = y; pz[r] = z; dist[r] = 1e10f;
    sp[i] = make_float4(x, y, z, 0.0f);
  }
  __syncthreads();
  float4 c = sp[0];
  if (tid == 0) { an[0] = c.x; an[1] = c.y; an[2] = c.z; }
  for (int s = 1; s < 256; ++s) {
    int par = s & 1;
#pragma unroll
    for (int r = 0; r < 2; ++r) {
      float dx = px[r] - c.x, dy = py[r] - c.y, dz = pz[r] - c.z;
      float d = fmaf(dx, dx, fmaf(dy, dy, dz * dz));
      dist[r] = fminf(dist[r], d);
    }
    float mloc = fmaxf(dist[0], dist[1]);
    float wmax = wave_max_dpp(mloc);
    float smax = __int_as_float(__builtin_amdgcn_readlane(__float_as_int(wmax), 63));
    unsigned int cidx = 0xFFFFFFFFu;
#pragma unroll
    for (int r = 1; r >= 0; --r) {
      unsigned long long m = __ballot(dist[r] == smax);
      unsigned int tz = (unsigned int)__builtin_ctzll(m | 0x8000000000000000ull);
      unsigned int cand = (unsigned int)(r * 512 + w * 64) + tz;
      cidx = m ? cand : cidx;
    }
    unsigned long long key =
        ((unsigned long long)__float_as_uint(smax) << 32) |
        (unsigned long long)(~cidx);
    if (lane == 0) keys[par][w] = key;
    __syncthreads();
    unsigned long long kv = keys[par][lane & 7];
    kv = dpp_max_u64<0xB1>(kv);
    kv = dpp_max_u64<0x4E>(kv);
    kv = dpp_max_u64<0x124>(kv);
    unsigned int bi = ~(unsigned int)(kv & 0xFFFFFFFFull);
    c = sp[bi];
    if (tid == 0) { an[s * 3 + 0] = c.x; an[s * 3 + 1] = c.y; an[s * 3 + 2] = c.z; }
  }
}

// ========== Ball query + P4D conv + ReLU; emits fp32 + bf16 + exact row stats ==========
__global__ __launch_bounds__(256) void conv_kernel(
    const float* __restrict__ xyzs, const float* __restrict__ anchors,
    const float* __restrict__ Wd, float* __restrict__ feats,
    bf16_t* __restrict__ featsb, float* __restrict__ stA0) {
  int bid = blockIdx.x;
  int tid = threadIdx.x;
  int j = bid & 255, to = (bid >> 8) & 3, b = bid >> 10;
  __shared__ float disp[96][4];
  __shared__ int idxbuf[3][32];
  __shared__ float red1[4], red2[4];
  const float* an = anchors + (size_t)((b * 4 + to) * 256 + j) * 3;
  float ax = an[0], ay = an[1], az = an[2];
  int w = tid >> 6, lane = tid & 63;
  if (w < 3) {
    int src = to + w - 1; src = src < 0 ? 0 : (src > 3 ? 3 : src);
    const float* nb = xyzs + (size_t)(b * 4 + src) * 1024 * 3;
    int cnt = 0;
    for (int ch = 0; ch < 16; ++ch) {
      if (cnt >= 32) break;
      int i = ch * 64 + lane;
      float dx = ax - nb[i * 3], dy = ay - nb[i * 3 + 1], dz = az - nb[i * 3 + 2];
      float d2 = dx * dx + dy * dy + dz * dz;
      bool in = d2 < 1.0f;
      unsigned long long mask = __ballot(in);
      if (in) {
        int pos = cnt + (int)__popcll(mask & ((1ull << lane) - 1ull));
        if (pos < 32) idxbuf[w][pos] = i;
      }
      cnt += (int)__popcll(mask);
    }
    if (cnt > 32) cnt = 32;
    if (lane >= cnt && lane < 32) idxbuf[w][lane] = (cnt > 0) ? idxbuf[w][0] : 0;
    if (lane < 32) {
      int ni = idxbuf[w][lane];
      int row = w * 32 + lane;
      disp[row][0] = nb[ni * 3 + 0] - ax;
      disp[row][1] = nb[ni * 3 + 1] - ay;
      disp[row][2] = nb[ni * 3 + 2] - az;
      disp[row][3] = (float)(w - 1);
    }
  }
  __syncthreads();
  int row = (b * 1024) + to * 256 + j;
  const float* wr0 = Wd + tid * 4;
  const float* wr1 = Wd + (tid + 256) * 4;
  float w00 = wr0[0], w01 = wr0[1], w02 = wr0[2], w03 = wr0[3];
  float w10 = wr1[0], w11 = wr1[1], w12 = wr1[2], w13 = wr1[3];
  float mx0 = -1e30f, mx1 = -1e30f;
#pragma unroll 8
  for (int nn = 0; nn < 96; ++nn) {
    float a0 = disp[nn][0], a1 = disp[nn][1], a2 = disp[nn][2], a3 = disp[nn][3];
    mx0 = fmaxf(mx0, a0 * w00 + a1 * w01 + a2 * w02 + a3 * w03);
    mx1 = fmaxf(mx1, a0 * w10 + a1 * w11 + a2 * w12 + a3 * w13);
  }
  float v0 = fmaxf(mx0, 0.0f), v1 = fmaxf(mx1, 0.0f);
  float* fout = feats + (size_t)row * 512;
  fout[tid] = v0;
  fout[tid + 256] = v1;
  featsb[(size_t)row * 512 + tid] = (bf16_t)v0;
  featsb[(size_t)row * 512 + tid + 256] = (bf16_t)v1;
  float s = v0 + v1;
  float q = v0 * v0 + v1 * v1;
#pragma unroll
  for (int off = 32; off >= 1; off >>= 1) {
    s += __shfl_xor(s, off, 64);
    q += __shfl_xor(q, off, 64);
  }
  if (lane == 0) { red1[w] = s; red2[w] = q; }
  __syncthreads();
  if (tid == 0) {
    stA0[2 * row] = red1[0] + red1[1] + red1[2] + red1[3];
    stA0[2 * row + 1] = red2[0] + red2[1] + red2[2] + red2[3];
  }
}

// ========================= bf16 MFMA GEMM (BK=64, single-buffer) =========================
template <int BM, int BN, bool GELU, bool BIAS, bool RES, bool OUTBF,
          bool LNIN, bool STATS>
__global__ __launch_bounds__(256) void gemm_bf16(
    const bf16_t* __restrict__ A, const bf16_t* __restrict__ W,
    const float* __restrict__ bias, const float* __restrict__ res,
    void* __restrict__ Cout, int Mn, int Nn, int Kn,
    const float* __restrict__ stats, const float* __restrict__ c2cb,
    float* __restrict__ statsOut, bf16_t* __restrict__ bcopy) {
  constexpr int BK = 64;
  constexpr int WM = BM / 2, WN = BN / 2;
  constexpr int MT = WM / 16, NT = WN / 16;
  constexpr int AIT = (BM * BK / 8) / 256;
  constexpr int BIT = (BN * BK / 8) / 256;
  __shared__ __align__(16) bf16_t As[BM * BK];
  __shared__ __align__(16) bf16_t Bs[BN * BK];
  int tid = threadIdx.x;
  int w = tid >> 6, lane = tid & 63;
  int wr = w >> 1, wc = w & 1;
  int m0 = blockIdx.y * BM, n0 = blockIdx.x * BN;
  int l15 = lane & 15, quad = lane >> 4;
  f32x4 acc[MT][NT] = {};

  const int a_fo = (wr * WM + l15) * BK + quad * 8;
  const int b_fo = (wc * WN + l15) * BK + quad * 8;

  for (int k0 = 0; k0 < Kn; k0 += BK) {
    __syncthreads();
#pragma unroll
    for (int i = 0; i < AIT; ++i) {
      int chunk = i * 256 + tid;
      int row = chunk >> 3, c8 = chunk & 7;
      async16(A + ((size_t)(m0 + row) * Kn + k0 + c8 * 8), As + chunk * 8);
    }
#pragma unroll
    for (int i = 0; i < BIT; ++i) {
      int chunk = i * 256 + tid;
      int row = chunk >> 3, c8 = chunk & 7;
      async16(W + ((size_t)(n0 + row) * Kn + k0 + c8 * 8), Bs + chunk * 8);
    }
    __syncthreads();
#pragma unroll
    for (int ks = 0; ks < 2; ++ks) {
      bf16x8 aF[MT], bF[NT];
#pragma unroll
      for (int mt = 0; mt < MT; ++mt)
        aF[mt] = *(const bf16x8*)&As[a_fo + mt * 16 * BK + ks * 32];
#pragma unroll
      for (int nt = 0; nt < NT; ++nt)
        bF[nt] = *(const bf16x8*)&Bs[b_fo + nt * 16 * BK + ks * 32];
#pragma unroll
      for (int mt = 0; mt < MT; ++mt)
#pragma unroll
        for (int nt = 0; nt < NT; ++nt)
          acc[mt][nt] = __builtin_amdgcn_mfma_f32_16x16x32_bf16(
              aF[mt], bF[nt], acc[mt][nt], 0, 0, 0);
    }
  }
  int rbase = quad * 4;
#pragma unroll
  for (int mt = 0; mt < MT; ++mt) {
#pragma unroll
    for (int reg = 0; reg < 4; ++reg) {
      int r = m0 + wr * WM + mt * 16 + rbase + reg;
      size_t roff = (size_t)r * Nn;
      float mu = 0.f, rs = 0.f;
      if (LNIN) {
        float s1 = stats[2 * r], s2 = stats[2 * r + 1];
        mu = s1 * (1.0f / 512.0f);
        float var = s2 * (1.0f / 512.0f) - mu * mu;
        rs = rsqrtf(var + 1e-5f);
      }
      float rsum = 0.f, rsq = 0.f;
#pragma unroll
      for (int nt = 0; nt < NT; ++nt) {
        int c = n0 + wc * WN + nt * 16 + l15;
        float v = acc[mt][nt][reg];
        if (LNIN) {
          float cc2 = c2cb[2 * c], ccb = c2cb[2 * c + 1];
          v = rs * v - rs * mu * cc2 + ccb;
        }
        if (BIAS) v += bias[c];
        if (GELU) v = v * 0.5f * (1.0f + erff(v * 0.7071067811865475f));
        if (RES) v += res[roff + c];
        if (OUTBF) ((bf16_t*)Cout)[roff + c] = (bf16_t)v;
        else ((float*)Cout)[roff + c] = v;
        if (STATS) {
          bcopy[roff + c] = (bf16_t)v;
          rsum += v; rsq += v * v;
        }
      }
      if (STATS) {
#pragma unroll
        for (int off = 1; off <= 8; off <<= 1) {
          rsum += __shfl_xor(rsum, off, 64);
          rsq += __shfl_xor(rsq, off, 64);
        }
        if (l15 == 0) {
          atomicAdd(&statsOut[2 * r], rsum);
          atomicAdd(&statsOut[2 * r + 1], rsq);
        }
      }
    }
  }
}

// ========================= Attention (MFMA flash, double-buffered) =========================
__global__ __launch_bounds__(256) void attn_kernel(
    const bf16_t* __restrict__ qkv, const float* __restrict__ xyzf,
    const float* __restrict__ Wsp, bf16_t* __restrict__ outp) {
  int bid = blockIdx.x;
  int qt = bid & 15, h = (bid >> 4) & 7, b = bid >> 7;
  int tid = threadIdx.x;
  int w = tid >> 6, lane = tid & 63;
  int l15 = lane & 15, quad = lane >> 4;

  __shared__ __align__(16) bf16_t Kb[2][64 * 64];
  __shared__ __align__(16) bf16_t Vt[2][64 * 72];
  __shared__ __align__(16) bf16_t Ps[4][16 * 72];
  __shared__ __align__(16) float4 Xs[2][64];

  const size_t tokbase = (size_t)b * 1024;
  int qbase = qt * 64 + w * 16;

  bf16x8 aQ[2];
  {
    const bf16_t* qp = qkv + (tokbase + qbase + l15) * 1536 + h * 64 + quad * 8;
    aQ[0] = *(const bf16x8*)(qp);
    aQ[1] = *(const bf16x8*)(qp + 32);
  }

  f32x4 oacc[4] = {};
  float lr[4] = {}, pxr[4] = {}, pyr[4] = {}, pzr[4] = {};

  auto stage = [&](int ch, int buf) {
    int j0 = ch * 64;
    int r0 = tid >> 3, seg = tid & 7;
    const bf16_t* g0 = qkv + (tokbase + j0 + r0) * 1536 + 512 + h * 64 + seg * 8;
    async16(g0, Kb[buf] + tid * 8);
    const bf16_t* g1 = qkv + (tokbase + j0 + 32 + r0) * 1536 + 512 + h * 64 + seg * 8;
    async16(g1, Kb[buf] + 2048 + tid * 8);
#pragma unroll
    for (int t = 0; t < 4; ++t) {
      int task = t * 256 + tid;
      int rp = task >> 5, c2 = task & 31;
      const uint32_t* vsrc = (const uint32_t*)(qkv + (tokbase + j0 + 2 * rp) * 1536 +
                                               1024 + h * 64 + 2 * c2);
      uint32_t a = vsrc[0];
      uint32_t bq = vsrc[768];
      uint32_t wlo = (a & 0xffffu) | (bq << 16);
      uint32_t whi = (a >> 16) | (bq & 0xffff0000u);
      uint32_t* vd = (uint32_t*)Vt[buf];
      vd[c2 * 72 + rp] = wlo;
      vd[c2 * 72 + 36 + rp] = whi;
    }
    if (tid < 64) {
      const float* xp = xyzf + (tokbase + j0 + tid) * 3;
      Xs[buf][tid] = make_float4(xp[0], xp[1], xp[2], 0.0f);
    }
  };

  stage(0, 0);
  for (int ch = 0; ch < 16; ++ch) {
    int cur = ch & 1;
    __syncthreads();
    if (ch + 1 < 16) stage(ch + 1, cur ^ 1);
    f32x4 sacc[4] = {};
#pragma unroll
    for (int ks = 0; ks < 2; ++ks)
#pragma unroll
      for (int nt = 0; nt < 4; ++nt) {
        bf16x8 bK = *(const bf16x8*)&Kb[cur][(nt * 16 + l15) * 64 + ks * 32 + quad * 8];
        sacc[nt] = __builtin_amdgcn_mfma_f32_16x16x32_bf16(aQ[ks], bK, sacc[nt], 0, 0, 0);
      }
#pragma unroll
    for (int nt = 0; nt < 4; ++nt) {
      float4 xk = Xs[cur][nt * 16 + l15];
#pragma unroll
      for (int reg = 0; reg < 4; ++reg) {
        float p = __expf(sacc[nt][reg] * 0.125f);
        bf16_t pb = (bf16_t)p;
        float pf = (float)pb;
        Ps[w][(quad * 4 + reg) * 72 + nt * 16 + l15] = pb;
        lr[reg] += pf;
        pxr[reg] = fmaf(pf, xk.x, pxr[reg]);
        pyr[reg] = fmaf(pf, xk.y, pyr[reg]);
        pzr[reg] = fmaf(pf, xk.z, pzr[reg]);
      }
    }
    bf16x8 aP[2];
    aP[0] = *(const bf16x8*)&Ps[w][l15 * 72 + quad * 8];
    aP[1] = *(const bf16x8*)&Ps[w][l15 * 72 + 32 + quad * 8];
#pragma unroll
    for (int ks = 0; ks < 2; ++ks)
#pragma unroll
      for (int ct = 0; ct < 4; ++ct) {
        bf16x8 bV = *(const bf16x8*)&Vt[cur][(ct * 16 + l15) * 72 + ks * 32 + quad * 8];
        oacc[ct] = __builtin_amdgcn_mfma_f32_16x16x32_bf16(aP[ks], bV, oacc[ct], 0, 0, 0);
      }
  }
#pragma unroll
  for (int reg = 0; reg < 4; ++reg) {
#pragma unroll
    for (int off = 1; off <= 8; off <<= 1) {
      lr[reg] += __shfl_xor(lr[reg], off, 64);
      pxr[reg] += __shfl_xor(pxr[reg], off, 64);
      pyr[reg] += __shfl_xor(pyr[reg], off, 64);
      pzr[reg] += __shfl_xor(pzr[reg], off, 64);
    }
  }
#pragma unroll
  for (int reg = 0; reg < 4; ++reg) {
    size_t tok = tokbase + qbase + quad * 4 + reg;
    float inv = 1.0f / lr[reg];
    const float* xqp = xyzf + tok * 3;
    float wd0 = pxr[reg] * inv - xqp[0];
    float wd1 = pyr[reg] * inv - xqp[1];
    float wd2 = pzr[reg] * inv - xqp[2];
#pragma unroll
    for (int ct = 0; ct < 4; ++ct) {
      int c = ct * 16 + l15;
      const float* wr = Wsp + c * 3;
      float dv = wd0 * wr[0] + wd1 * wr[1] + wd2 * wr[2];
      outp[tok * 512 + h * 64 + c] = (bf16_t)(oacc[ct][reg] * inv + dv);
    }
  }
}

// ========================= launch =========================
extern "C" void kernel_launch(void* const* d_in, const int* in_sizes, int n_in,
                              void* d_out, int out_size, void* d_ws, size_t ws_size,
                              hipStream_t stream) {
  const float* xyzs = (const float*)d_in[0];
  const float* Wd   = (const float*)d_in[1];
  const float* Wqkv = (const float*)d_in[2];
  const float* Wsp  = (const float*)d_in[3];
  const float* Wout = (const float*)d_in[4];
  const float* bout = (const float*)d_in[5];
  const float* ln1g = (const float*)d_in[6];
  const float* ln1b = (const float*)d_in[7];
  const float* Wff1 = (const float*)d_in[8];
  const float* bff1 = (const float*)d_in[9];
  const float* Wff2 = (const float*)d_in[10];
  const float* bff2 = (const float*)d_in[11];
  const float* ln2g = (const float*)d_in[12];
  const float* ln2b = (const float*)d_in[13];
  float* out = (float*)d_out;

  float* ws = (float*)d_ws;
  float* anchors = ws;                         // 8192 f32
  float* featsA  = ws + 8192;                  // 2048*512 f32
  float* featsB  = featsA + 1048576;           // 2048*512 f32
  float* big     = featsB + 1048576;           // 12MB region
  bf16_t* bigb   = (bf16_t*)big;               // qkv out / ff1 out bf16
  bf16_t* featsAb = (bf16_t*)(big + 3145728);  // 2048*512 bf16 (raw x)
  bf16_t* attob  = featsAb + 1048576;          // 2048*512 bf16
  bf16_t* featsBb = attob + 1048576;           // 2048*512 bf16 (raw x)
  bf16_t* wq_b   = featsBb + 1048576;          // 2*1536*512
  bf16_t* wo_b   = wq_b + 1572864;             // 2*512*512
  bf16_t* w1_b   = wo_b + 524288;              // 2*2048*512
  bf16_t* w2_b   = w1_b + 2097152;             // 2*512*2048
  float* stA0    = (float*)(w2_b + 2097152);   // 4096 f (exact, conv)
  float* statsZ  = stA0 + 4096;                // 12288 f zeroed: stB0|stB1|stA1
  float* stB0    = statsZ;
  float* stB1    = statsZ + 4096;
  float* stA1    = statsZ + 8192;
  float* c2cb_q  = statsZ + 12288;             // 2*1536*2 f
  float* c2cb_f  = c2cb_q + 6144;              // 2*2048*2 f

  fps_cvt_kernel<<<3982, 512, 0, stream>>>(
      xyzs, anchors, Wqkv, wq_b, Wout, wo_b, Wff1, w1_b, Wff2, w2_b,
      ln1g, ln1b, ln2g, ln2b, c2cb_q, c2cb_f, statsZ);
  conv_kernel<<<2048, 256, 0, stream>>>(xyzs, anchors, Wd, featsA, featsAb, stA0);

  for (int dep = 0; dep < 2; ++dep) {
    const float* stA = dep ? stA1 : stA0;
    float* stB = dep ? stB1 : stB0;
    // qkv = LN1-fold GEMM (64x64 tiles: 768 blocks = 3/CU balanced)
    gemm_bf16<64, 64, false, false, false, true, true, false>
        <<<dim3(24, 32), 256, 0, stream>>>(
        featsAb, wq_b + (size_t)dep * 786432, nullptr, nullptr, bigb,
        2048, 1536, 512, stA, c2cb_q + (size_t)dep * 3072, nullptr, nullptr);
    attn_kernel<<<256, 256, 0, stream>>>(bigb, anchors, Wsp + dep * 192, attob);
    gemm_bf16<32, 64, true, true, true, false, false, true>
        <<<dim3(8, 64), 256, 0, stream>>>(
        attob, wo_b + (size_t)dep * 262144, bout + dep * 512, featsA, featsB,
        2048, 512, 512, nullptr, nullptr, stB, featsBb);
    // ff1 = LN2-fold GEMM (64x64 tiles: 1024 blocks = 4/CU)
    gemm_bf16<64, 64, true, true, false, true, true, false>
        <<<dim3(32, 32), 256, 0, stream>>>(
        featsBb, w1_b + (size_t)dep * 1048576, bff1 + dep * 2048, nullptr, bigb,
        2048, 2048, 512, stB, c2cb_f + (size_t)dep * 4096, nullptr, nullptr);
    if (dep == 0) {
      gemm_bf16<32, 64, false, true, true, false, false, true>
          <<<dim3(8, 64), 256, 0, stream>>>(
          bigb, w2_b, bff2, featsB, featsA,
          2048, 512, 2048, nullptr, nullptr, stA1, featsAb);
    } else {
      gemm_bf16<32, 64, false, true, true, false, false, false>
          <<<dim3(8, 64), 256, 0, stream>>>(
          bigb, w2_b + 1048576, bff2 + 512, featsB, out,
          2048, 512, 2048, nullptr, nullptr, nullptr, nullptr);
    }
  }
}